// Round 8
// baseline (88.376 us; speedup 1.0000x reference)
//
#include <hip/hip_runtime.h>

#define B_ 8
#define C_ 3
#define R_ 8
#define H_ 512
#define W_ 512
#define HW_ (H_*W_)
#define S_ 1024
#define CB_ 25
#define TB_ 10

// output offsets (floats)
#define O_AREA 0
#define O_BBOX 8192
#define O_COLOR 40960
#define O_TEX 655360
#define O_GRADS 2621440
#define OUT_TOT 15204352

// K1 block roles
#define NTEX 192                    // full-plane tex blocks
#define NCOL 24                     // full-plane color blocks
#define NBB  256                    // 8 images x 32 chunks
#define NHIST (NTEX + NCOL + NBB)   // 472
#define NCONV 768                   // 768*1024 threads x 8 px = 6,291,456 input px exact
#define NGRID1 (NHIST + NCONV)      // 1240

#define SCR_WORDS (NBB * 2048)      // 524,288 u32 = 2 MB
#define NEED_WS ((size_t)SCR_WORDS * 4)
// fallback scratch = last 2 MB of out (grads planes of bc=23); K1 conv then stops
// at rid<RID_SAFE (bc<23) and K3 finishes bc=23 after the merge consumed scratch.
#define RID_ALL  786432             // (B*C*HW)/8
#define RID_SAFE 753664             // (23*HW)/8

__device__ __forceinline__ void conv_run(const float* __restrict__ img,
                                         float* __restrict__ out, int rid) {
  const int px0 = rid << 3;            // global input pixel, 8-aligned
  const int pix0 = px0 & (HW_ - 1);
  const int bc = px0 >> 18;            // 0..23
  const int x0 = pix0 & (W_ - 1);
  const int y = pix0 >> 9;
  const float* im = img + (size_t)bc * HW_ + pix0;
  const bool ym = y > 0, yp = y < H_ - 1, xm = x0 > 0, xp = x0 < W_ - 8;
  float r0[10], r1[10], r2[10];
  {
    const float4 a = *(const float4*)(im);
    const float4 c = *(const float4*)(im + 4);
    r1[1]=a.x; r1[2]=a.y; r1[3]=a.z; r1[4]=a.w;
    r1[5]=c.x; r1[6]=c.y; r1[7]=c.z; r1[8]=c.w;
    r1[0] = xm ? im[-1] : 0.f;  r1[9] = xp ? im[8] : 0.f;
  }
  if (ym) {
    const float* p = im - W_;
    const float4 a = *(const float4*)(p);
    const float4 c = *(const float4*)(p + 4);
    r0[1]=a.x; r0[2]=a.y; r0[3]=a.z; r0[4]=a.w;
    r0[5]=c.x; r0[6]=c.y; r0[7]=c.z; r0[8]=c.w;
    r0[0] = xm ? p[-1] : 0.f;  r0[9] = xp ? p[8] : 0.f;
  } else {
    #pragma unroll
    for (int i = 0; i < 10; ++i) r0[i] = 0.f;
  }
  if (yp) {
    const float* p = im + W_;
    const float4 a = *(const float4*)(p);
    const float4 c = *(const float4*)(p + 4);
    r2[1]=a.x; r2[2]=a.y; r2[3]=a.z; r2[4]=a.w;
    r2[5]=c.x; r2[6]=c.y; r2[7]=c.z; r2[8]=c.w;
    r2[0] = xm ? p[-1] : 0.f;  r2[9] = xp ? p[8] : 0.f;
  } else {
    #pragma unroll
    for (int i = 0; i < 10; ++i) r2[i] = 0.f;
  }
  float cs[10], dv[10];
  #pragma unroll
  for (int c = 0; c < 10; ++c) {
    cs[c] = 3.f * (r0[c] + r2[c]) + 10.f * r1[c];
    dv[c] = r2[c] - r0[c];
  }
  float gx[8], gy[8];
  #pragma unroll
  for (int k = 0; k < 8; ++k) {
    gx[k] = cs[k + 2] - cs[k];
    gy[k] = 3.f * (dv[k] + dv[k + 2]) + 10.f * dv[k + 1];
  }
  float* og = out + O_GRADS + (size_t)(bc * 2) * HW_ + pix0;
  *(float4*)(og)     = make_float4(gx[0], gx[1], gx[2], gx[3]);
  *(float4*)(og + 4) = make_float4(gx[4], gx[5], gx[6], gx[7]);
  float* oh = og + HW_;
  *(float4*)(oh)     = make_float4(gy[0], gy[1], gy[2], gy[3]);
  *(float4*)(oh + 4) = make_float4(gy[4], gy[5], gy[6], gy[7]);
}

// ================= K1: fused hist + bbox partials + conv =================
__global__ __launch_bounds__(1024) void k_fused(
    const float* __restrict__ img,
    const int* __restrict__ imgs_bins,
    const int* __restrict__ grads_bins,
    const int* __restrict__ lab,
    float* __restrict__ out,
    unsigned* __restrict__ scr,
    int ridHi) {
  __shared__ unsigned smem[12800];   // 51.2 KB union
  const int bid = blockIdx.x;
  const int tid = threadIdx.x;

  if (bid >= NHIST) {
    // ---- conv: one 8-px run per thread ----
    const int rid = (bid - NHIST) * 1024 + tid;
    if (rid < ridHi) conv_run(img, out, rid);
  } else if (bid < NTEX) {
    // ---- texture hist plane (b, cr): int LDS hist, exclusive final write ----
    const int plane = bid;                  // b*24 + cr
    const int b = plane / (C_*R_);
    const int cr = plane - b * (C_*R_);
    int* h = (int*)smem;                    // 10240 ints (40 KB)
    for (int i = tid; i < S_*TB_; i += 1024) h[i] = 0;
    __syncthreads();
    const int4* bp = (const int4*)(grads_bins + (size_t)plane * HW_);
    const int4* lp = (const int4*)(lab + (size_t)b * HW_);
    int4 cb = bp[tid], cl = lp[tid];
    #pragma unroll 1
    for (int it = 1; it < 64; ++it) {
      const int4 nb = bp[it * 1024 + tid];   // rolling prefetch
      const int4 nl = lp[it * 1024 + tid];
      atomicAdd(&h[cl.x*TB_ + cb.x], 1);
      atomicAdd(&h[cl.y*TB_ + cb.y], 1);
      atomicAdd(&h[cl.z*TB_ + cb.z], 1);
      atomicAdd(&h[cl.w*TB_ + cb.w], 1);
      cb = nb; cl = nl;
    }
    atomicAdd(&h[cl.x*TB_ + cb.x], 1);
    atomicAdd(&h[cl.y*TB_ + cb.y], 1);
    atomicAdd(&h[cl.z*TB_ + cb.z], 1);
    atomicAdd(&h[cl.w*TB_ + cb.w], 1);
    __syncthreads();
    {
      const int base = tid * TB_;
      int s = 0;
      #pragma unroll
      for (int t = 0; t < TB_; ++t) s += h[base + t];
      const float inv = 1.0f / ((float)s * 24.0f + 1e-12f);
      float* o = out + O_TEX + (size_t)b * (S_ * 240) + tid * 240 + cr * TB_;
      #pragma unroll
      for (int t = 0; t < TB_; ++t) o[t] = (float)h[base + t] * inv;
      if (cr == 0) out[O_AREA + b * S_ + tid] = (float)s;
    }
  } else if (bid < NTEX + NCOL) {
    // ---- color hist plane (b,c): u16-packed LDS, exclusive final write ----
    const int plane = bid - NTEX;           // b*3 + c
    const int b = plane / C_;
    const int c = plane - b * C_;
    unsigned* h = smem;                     // 12800 words
    for (int i = tid; i < 12800; i += 1024) h[i] = 0;
    __syncthreads();
    const int4* bp = (const int4*)(imgs_bins + (size_t)plane * HW_);
    const int4* lp = (const int4*)(lab + (size_t)b * HW_);
    int4 cb = bp[tid], cl = lp[tid];
    #pragma unroll 1
    for (int it = 1; it < 64; ++it) {
      const int4 nb = bp[it * 1024 + tid];
      const int4 nl = lp[it * 1024 + tid];
      const int j0 = cl.x*CB_ + cb.x;
      const int j1 = cl.y*CB_ + cb.y;
      const int j2 = cl.z*CB_ + cb.z;
      const int j3 = cl.w*CB_ + cb.w;
      atomicAdd(&h[j0 >> 1], 1u << ((j0 & 1) << 4));
      atomicAdd(&h[j1 >> 1], 1u << ((j1 & 1) << 4));
      atomicAdd(&h[j2 >> 1], 1u << ((j2 & 1) << 4));
      atomicAdd(&h[j3 >> 1], 1u << ((j3 & 1) << 4));
      cb = nb; cl = nl;
    }
    {
      const int j0 = cl.x*CB_ + cb.x;
      const int j1 = cl.y*CB_ + cb.y;
      const int j2 = cl.z*CB_ + cb.z;
      const int j3 = cl.w*CB_ + cb.w;
      atomicAdd(&h[j0 >> 1], 1u << ((j0 & 1) << 4));
      atomicAdd(&h[j1 >> 1], 1u << ((j1 & 1) << 4));
      atomicAdd(&h[j2 >> 1], 1u << ((j2 & 1) << 4));
      atomicAdd(&h[j3 >> 1], 1u << ((j3 & 1) << 4));
    }
    __syncthreads();
    {
      int s = 0;
      #pragma unroll
      for (int ci = 0; ci < CB_; ++ci) {
        const int j = tid * CB_ + ci;
        s += (int)((h[j >> 1] >> ((j & 1) << 4)) & 0xFFFFu);
      }
      const float inv = 1.0f / ((float)s * 3.0f + 1e-12f);
      float* o = out + O_COLOR + (size_t)b * (S_ * 75) + tid * 75 + c * CB_;
      #pragma unroll
      for (int ci = 0; ci < CB_; ++ci) {
        const int j = tid * CB_ + ci;
        o[ci] = (float)((h[j >> 1] >> ((j & 1) << 4)) & 0xFFFFu) * inv;
      }
    }
  } else {
    // ---- bbox chunk (b, 1/32 image): LDS partial -> plain-store scratch ----
    const int rid2 = bid - NTEX - NCOL;     // 0..255
    const int b = rid2 >> 5, q = rid2 & 31;
    int* mn = (int*)smem;
    mn[tid] = W_; mn[1024 + tid] = H_; mn[2048 + tid] = 0; mn[3072 + tid] = 0;
    __syncthreads();
    const int4* lp = (const int4*)(lab + (size_t)b * HW_) + q * 2048;
    const int4 l0 = lp[tid], l1 = lp[tid + 1024];
    const int p0 = (q * 2048 + tid) * 4, p1 = p0 + 4096;
    #define BB(L,P) { const int yy = (P) >> 9, xx = (P) & (W_-1); \
      atomicMin(&mn[L], xx); atomicMin(&mn[1024 + (L)], yy); \
      atomicMax(&mn[2048 + (L)], xx); atomicMax(&mn[3072 + (L)], yy); }
    BB(l0.x, p0) BB(l0.y, p0+1) BB(l0.z, p0+2) BB(l0.w, p0+3)
    BB(l1.x, p1) BB(l1.y, p1+1) BB(l1.z, p1+2) BB(l1.w, p1+3)
    #undef BB
    __syncthreads();
    unsigned* dst = scr + (size_t)rid2 * 2048;
    dst[tid]        = (unsigned)mn[tid]        | ((unsigned)mn[1024 + tid] << 16);
    dst[1024 + tid] = (unsigned)mn[2048 + tid] | ((unsigned)mn[3072 + tid] << 16);
  }
}

// ================= K2: bbox merge (8 blocks) =================
__global__ __launch_bounds__(1024) void k_bb_merge(float* __restrict__ out,
                                                   const unsigned* __restrict__ scr) {
  const int b = blockIdx.x, l = threadIdx.x;
  int xmn = W_, ymn = H_, xmx = 0, ymx = 0;
  const unsigned* p = scr + (size_t)(b * 32) * 2048 + l;
  #pragma unroll
  for (int k = 0; k < 32; ++k) {
    const unsigned w0 = p[k * 2048];
    const unsigned w1 = p[k * 2048 + 1024];
    xmn = min(xmn, (int)(w0 & 0xFFFFu)); ymn = min(ymn, (int)(w0 >> 16));
    xmx = max(xmx, (int)(w1 & 0xFFFFu)); ymx = max(ymx, (int)(w1 >> 16));
  }
  float4 v;
  v.x = (float)xmn; v.y = (float)ymn;
  v.z = (float)(xmx - xmn); v.w = (float)(ymx - ymn);
  ((float4*)(out + O_BBOX))[b * S_ + l] = v;
}

// ================= K3 (fallback only): conv tail bc=23 =================
__global__ __launch_bounds__(1024) void k_conv_tail(const float* __restrict__ img,
                                                    float* __restrict__ out) {
  conv_run(img, out, RID_SAFE + blockIdx.x * 1024 + threadIdx.x);
}

extern "C" void kernel_launch(void* const* d_in, const int* in_sizes, int n_in,
                              void* d_out, int out_size, void* d_ws, size_t ws_size,
                              hipStream_t stream) {
  const float* img = (const float*)d_in[0];
  const int* imgs_bins = (const int*)d_in[1];
  const int* grads_bins = (const int*)d_in[2];
  const int* reg_lab = (const int*)d_in[3];
  float* out = (float*)d_out;

  const bool ws_ok = ws_size >= NEED_WS;
  unsigned* scr = ws_ok ? (unsigned*)d_ws : (unsigned*)(out + (OUT_TOT - SCR_WORDS));
  const int ridHi = ws_ok ? RID_ALL : RID_SAFE;

  hipLaunchKernelGGL(k_fused, dim3(NGRID1), dim3(1024), 0, stream,
                     img, imgs_bins, grads_bins, reg_lab, out, scr, ridHi);
  hipLaunchKernelGGL(k_bb_merge, dim3(8), dim3(1024), 0, stream, out, scr);
  if (!ws_ok) {
    hipLaunchKernelGGL(k_conv_tail, dim3((RID_ALL - RID_SAFE) / 1024), dim3(1024),
                       0, stream, img, out);
  }
}

// Round 9
// 83.293 us; speedup vs baseline: 1.0610x; 1.0610x over previous
//
#include <hip/hip_runtime.h>

#define B_ 8
#define C_ 3
#define R_ 8
#define H_ 512
#define W_ 512
#define HW_ (H_*W_)
#define S_ 1024
#define CB_ 25
#define TB_ 10

// output offsets (floats)
#define O_AREA 0
#define O_BBOX 8192
#define O_COLOR 40960
#define O_TEX 655360
#define O_GRADS 2621440

// block roles: single launch, 512 blocks = 2 per CU
#define NTEX 192                    // full-plane tex blocks
#define NCOL 24                     // full-plane color blocks
#define NBB  8                      // full-image bbox blocks
#define NHIST (NTEX + NCOL + NBB)   // 224
#define NCONV 288                   // long-lived grid-stride conv blocks
#define NGRID (NHIST + NCONV)       // 512

#define RID_ALL 786432              // (B*C*HW)/8 input-pixel runs

__device__ __forceinline__ void conv_run(const float* __restrict__ img,
                                         float* __restrict__ out, int rid) {
  const int px0 = rid << 3;            // global input pixel, 8-aligned
  const int pix0 = px0 & (HW_ - 1);
  const int bc = px0 >> 18;            // 0..23
  const int x0 = pix0 & (W_ - 1);
  const int y = pix0 >> 9;
  const float* im = img + (size_t)bc * HW_ + pix0;
  const bool ym = y > 0, yp = y < H_ - 1, xm = x0 > 0, xp = x0 < W_ - 8;
  float r0[10], r1[10], r2[10];
  {
    const float4 a = *(const float4*)(im);
    const float4 c = *(const float4*)(im + 4);
    r1[1]=a.x; r1[2]=a.y; r1[3]=a.z; r1[4]=a.w;
    r1[5]=c.x; r1[6]=c.y; r1[7]=c.z; r1[8]=c.w;
    r1[0] = xm ? im[-1] : 0.f;  r1[9] = xp ? im[8] : 0.f;
  }
  if (ym) {
    const float* p = im - W_;
    const float4 a = *(const float4*)(p);
    const float4 c = *(const float4*)(p + 4);
    r0[1]=a.x; r0[2]=a.y; r0[3]=a.z; r0[4]=a.w;
    r0[5]=c.x; r0[6]=c.y; r0[7]=c.z; r0[8]=c.w;
    r0[0] = xm ? p[-1] : 0.f;  r0[9] = xp ? p[8] : 0.f;
  } else {
    #pragma unroll
    for (int i = 0; i < 10; ++i) r0[i] = 0.f;
  }
  if (yp) {
    const float* p = im + W_;
    const float4 a = *(const float4*)(p);
    const float4 c = *(const float4*)(p + 4);
    r2[1]=a.x; r2[2]=a.y; r2[3]=a.z; r2[4]=a.w;
    r2[5]=c.x; r2[6]=c.y; r2[7]=c.z; r2[8]=c.w;
    r2[0] = xm ? p[-1] : 0.f;  r2[9] = xp ? p[8] : 0.f;
  } else {
    #pragma unroll
    for (int i = 0; i < 10; ++i) r2[i] = 0.f;
  }
  float cs[10], dv[10];
  #pragma unroll
  for (int c = 0; c < 10; ++c) {
    cs[c] = 3.f * (r0[c] + r2[c]) + 10.f * r1[c];
    dv[c] = r2[c] - r0[c];
  }
  float gx[8], gy[8];
  #pragma unroll
  for (int k = 0; k < 8; ++k) {
    gx[k] = cs[k + 2] - cs[k];
    gy[k] = 3.f * (dv[k] + dv[k + 2]) + 10.f * dv[k + 1];
  }
  float* og = out + O_GRADS + (size_t)(bc * 2) * HW_ + pix0;
  *(float4*)(og)     = make_float4(gx[0], gx[1], gx[2], gx[3]);
  *(float4*)(og + 4) = make_float4(gx[4], gx[5], gx[6], gx[7]);
  float* oh = og + HW_;
  *(float4*)(oh)     = make_float4(gy[0], gy[1], gy[2], gy[3]);
  *(float4*)(oh + 4) = make_float4(gy[4], gy[5], gy[6], gy[7]);
}

// ================= single fused kernel =================
__global__ __launch_bounds__(1024) void k_fused(
    const float* __restrict__ img,
    const int* __restrict__ imgs_bins,
    const int* __restrict__ grads_bins,
    const int* __restrict__ lab,
    float* __restrict__ out) {
  __shared__ unsigned smem[12800];   // 51.2 KB union
  const int bid = blockIdx.x;
  const int tid = threadIdx.x;

  if (bid >= NHIST) {
    // ---- conv: long-lived grid-stride loop over 8-px runs ----
    for (int rid = (bid - NHIST) * 1024 + tid; rid < RID_ALL; rid += NCONV * 1024)
      conv_run(img, out, rid);
  } else if (bid < NTEX) {
    // ---- texture hist plane (b, cr): int LDS hist, exclusive final write ----
    const int plane = bid;                  // b*24 + cr
    const int b = plane / (C_*R_);
    const int cr = plane - b * (C_*R_);
    int* h = (int*)smem;                    // 10240 ints (40 KB)
    for (int i = tid; i < S_*TB_; i += 1024) h[i] = 0;
    __syncthreads();
    const int4* bp = (const int4*)(grads_bins + (size_t)plane * HW_);
    const int4* lp = (const int4*)(lab + (size_t)b * HW_);
    int4 cb = bp[tid], cl = lp[tid];
    #pragma unroll 1
    for (int it = 1; it < 64; ++it) {
      const int4 nb = bp[it * 1024 + tid];   // rolling prefetch
      const int4 nl = lp[it * 1024 + tid];
      atomicAdd(&h[cl.x*TB_ + cb.x], 1);
      atomicAdd(&h[cl.y*TB_ + cb.y], 1);
      atomicAdd(&h[cl.z*TB_ + cb.z], 1);
      atomicAdd(&h[cl.w*TB_ + cb.w], 1);
      cb = nb; cl = nl;
    }
    atomicAdd(&h[cl.x*TB_ + cb.x], 1);
    atomicAdd(&h[cl.y*TB_ + cb.y], 1);
    atomicAdd(&h[cl.z*TB_ + cb.z], 1);
    atomicAdd(&h[cl.w*TB_ + cb.w], 1);
    __syncthreads();
    {
      const int base = tid * TB_;
      int s = 0;
      #pragma unroll
      for (int t = 0; t < TB_; ++t) s += h[base + t];
      const float inv = 1.0f / ((float)s * 24.0f + 1e-12f);
      float* o = out + O_TEX + (size_t)b * (S_ * 240) + tid * 240 + cr * TB_;
      #pragma unroll
      for (int t = 0; t < TB_; ++t) o[t] = (float)h[base + t] * inv;
      if (cr == 0) out[O_AREA + b * S_ + tid] = (float)s;
    }
  } else if (bid < NTEX + NCOL) {
    // ---- color hist plane (b,c): u16-packed LDS, exclusive final write ----
    const int plane = bid - NTEX;           // b*3 + c
    const int b = plane / C_;
    const int c = plane - b * C_;
    unsigned* h = smem;                     // 12800 words
    for (int i = tid; i < 12800; i += 1024) h[i] = 0;
    __syncthreads();
    const int4* bp = (const int4*)(imgs_bins + (size_t)plane * HW_);
    const int4* lp = (const int4*)(lab + (size_t)b * HW_);
    int4 cb = bp[tid], cl = lp[tid];
    #pragma unroll 1
    for (int it = 1; it < 64; ++it) {
      const int4 nb = bp[it * 1024 + tid];
      const int4 nl = lp[it * 1024 + tid];
      const int j0 = cl.x*CB_ + cb.x;
      const int j1 = cl.y*CB_ + cb.y;
      const int j2 = cl.z*CB_ + cb.z;
      const int j3 = cl.w*CB_ + cb.w;
      atomicAdd(&h[j0 >> 1], 1u << ((j0 & 1) << 4));
      atomicAdd(&h[j1 >> 1], 1u << ((j1 & 1) << 4));
      atomicAdd(&h[j2 >> 1], 1u << ((j2 & 1) << 4));
      atomicAdd(&h[j3 >> 1], 1u << ((j3 & 1) << 4));
      cb = nb; cl = nl;
    }
    {
      const int j0 = cl.x*CB_ + cb.x;
      const int j1 = cl.y*CB_ + cb.y;
      const int j2 = cl.z*CB_ + cb.z;
      const int j3 = cl.w*CB_ + cb.w;
      atomicAdd(&h[j0 >> 1], 1u << ((j0 & 1) << 4));
      atomicAdd(&h[j1 >> 1], 1u << ((j1 & 1) << 4));
      atomicAdd(&h[j2 >> 1], 1u << ((j2 & 1) << 4));
      atomicAdd(&h[j3 >> 1], 1u << ((j3 & 1) << 4));
    }
    __syncthreads();
    {
      int s = 0;
      #pragma unroll
      for (int ci = 0; ci < CB_; ++ci) {
        const int j = tid * CB_ + ci;
        s += (int)((h[j >> 1] >> ((j & 1) << 4)) & 0xFFFFu);
      }
      const float inv = 1.0f / ((float)s * 3.0f + 1e-12f);
      float* o = out + O_COLOR + (size_t)b * (S_ * 75) + tid * 75 + c * CB_;
      #pragma unroll
      for (int ci = 0; ci < CB_; ++ci) {
        const int j = tid * CB_ + ci;
        o[ci] = (float)((h[j >> 1] >> ((j & 1) << 4)) & 0xFFFFu) * inv;
      }
    }
  } else {
    // ---- bbox for image b: full image, LDS min/max, exclusive final write ----
    const int b = bid - NTEX - NCOL;
    int* mn = (int*)smem;   // xmin[1024], ymin[1024], xmax[1024], ymax[1024]
    mn[tid] = W_; mn[1024 + tid] = H_; mn[2048 + tid] = 0; mn[3072 + tid] = 0;
    __syncthreads();
    const int4* lp = (const int4*)(lab + (size_t)b * HW_);
    int4 cl = lp[tid];
    #pragma unroll 1
    for (int it = 1; it < 64; ++it) {
      const int4 nl = lp[it * 1024 + tid];   // rolling prefetch
      const int p = ((it - 1) * 1024 + tid) * 4;
      const int y = p >> 9;
      const int x = p & (W_ - 1);   // 4-aligned: x..x+3 same row
      atomicMin(&mn[cl.x], x);       atomicMin(&mn[1024 + cl.x], y);
      atomicMax(&mn[2048 + cl.x], x);     atomicMax(&mn[3072 + cl.x], y);
      atomicMin(&mn[cl.y], x + 1);   atomicMin(&mn[1024 + cl.y], y);
      atomicMax(&mn[2048 + cl.y], x + 1); atomicMax(&mn[3072 + cl.y], y);
      atomicMin(&mn[cl.z], x + 2);   atomicMin(&mn[1024 + cl.z], y);
      atomicMax(&mn[2048 + cl.z], x + 2); atomicMax(&mn[3072 + cl.z], y);
      atomicMin(&mn[cl.w], x + 3);   atomicMin(&mn[1024 + cl.w], y);
      atomicMax(&mn[2048 + cl.w], x + 3); atomicMax(&mn[3072 + cl.w], y);
      cl = nl;
    }
    {
      const int p = (63 * 1024 + tid) * 4;
      const int y = p >> 9;
      const int x = p & (W_ - 1);
      atomicMin(&mn[cl.x], x);       atomicMin(&mn[1024 + cl.x], y);
      atomicMax(&mn[2048 + cl.x], x);     atomicMax(&mn[3072 + cl.x], y);
      atomicMin(&mn[cl.y], x + 1);   atomicMin(&mn[1024 + cl.y], y);
      atomicMax(&mn[2048 + cl.y], x + 1); atomicMax(&mn[3072 + cl.y], y);
      atomicMin(&mn[cl.z], x + 2);   atomicMin(&mn[1024 + cl.z], y);
      atomicMax(&mn[2048 + cl.z], x + 2); atomicMax(&mn[3072 + cl.z], y);
      atomicMin(&mn[cl.w], x + 3);   atomicMin(&mn[1024 + cl.w], y);
      atomicMax(&mn[2048 + cl.w], x + 3); atomicMax(&mn[3072 + cl.w], y);
    }
    __syncthreads();
    {
      const int xmn = mn[tid], ymn = mn[1024 + tid];
      const int xmx = mn[2048 + tid], ymx = mn[3072 + tid];
      float4 v;
      v.x = (float)xmn; v.y = (float)ymn;
      v.z = (float)(xmx - xmn); v.w = (float)(ymx - ymn);
      ((float4*)(out + O_BBOX))[b * S_ + tid] = v;
    }
  }
}

extern "C" void kernel_launch(void* const* d_in, const int* in_sizes, int n_in,
                              void* d_out, int out_size, void* d_ws, size_t ws_size,
                              hipStream_t stream) {
  const float* img = (const float*)d_in[0];
  const int* imgs_bins = (const int*)d_in[1];
  const int* grads_bins = (const int*)d_in[2];
  const int* reg_lab = (const int*)d_in[3];
  float* out = (float*)d_out;

  hipLaunchKernelGGL(k_fused, dim3(NGRID), dim3(1024), 0, stream,
                     img, imgs_bins, grads_bins, reg_lab, out);
}

// Round 10
// 79.236 us; speedup vs baseline: 1.1153x; 1.0512x over previous
//
#include <hip/hip_runtime.h>

#define B_ 8
#define C_ 3
#define R_ 8
#define H_ 512
#define W_ 512
#define HW_ (H_*W_)
#define S_ 1024
#define CB_ 25
#define TB_ 10

// output offsets (floats)
#define O_AREA 0
#define O_BBOX 8192
#define O_COLOR 40960
#define O_TEX 655360
#define O_GRADS 2621440

// block roles (R3 layout exactly)
#define NBBOX 8
#define NTEX (B_*C_*R_)        // 192
#define NCOL (B_*C_)           // 24
#define NHIST (NBBOX + NTEX + NCOL)   // 224
#define NCONV 1024
#define NGRID (NHIST + NCONV)

__global__ __launch_bounds__(1024) void k_fused(
    const float* __restrict__ img,
    const int* __restrict__ imgs_bins,
    const int* __restrict__ grads_bins,
    const int* __restrict__ lab,
    float* __restrict__ out) {
  __shared__ unsigned smem[12800];   // 51.2 KB union
  const int bid = blockIdx.x;
  const int tid = threadIdx.x;

  if (bid < NBBOX) {
    // ---------- bbox for image b: LDS min/max, exclusive final write ----------
    __builtin_amdgcn_s_setprio(1);   // critical-path wave priority
    const int b = bid;
    int* mn = (int*)smem;   // xmin[S], ymin[S], xmax[S], ymax[S] = 16 KB
    for (int i = tid; i < S_; i += 1024) {
      mn[i] = W_; mn[S_ + i] = H_; mn[2*S_ + i] = 0; mn[3*S_ + i] = 0;
    }
    __syncthreads();
    const int4* lp = (const int4*)(lab + (size_t)b * HW_);
    for (int t = tid; t < HW_/4; t += 1024) {
      const int4 lv = lp[t];
      const int p = t * 4;
      const int y = p >> 9;
      const int x = p & (W_ - 1);   // W=512, 4-aligned: x..x+3 same row
      atomicMin(&mn[lv.x], x);       atomicMin(&mn[S_ + lv.x], y);
      atomicMax(&mn[2*S_ + lv.x], x);   atomicMax(&mn[3*S_ + lv.x], y);
      atomicMin(&mn[lv.y], x + 1);   atomicMin(&mn[S_ + lv.y], y);
      atomicMax(&mn[2*S_ + lv.y], x + 1); atomicMax(&mn[3*S_ + lv.y], y);
      atomicMin(&mn[lv.z], x + 2);   atomicMin(&mn[S_ + lv.z], y);
      atomicMax(&mn[2*S_ + lv.z], x + 2); atomicMax(&mn[3*S_ + lv.z], y);
      atomicMin(&mn[lv.w], x + 3);   atomicMin(&mn[S_ + lv.w], y);
      atomicMax(&mn[2*S_ + lv.w], x + 3); atomicMax(&mn[3*S_ + lv.w], y);
    }
    __syncthreads();
    __builtin_amdgcn_s_setprio(0);
    // thread l owns label l (blockDim == S)
    {
      const int xmn = mn[tid], ymn = mn[S_ + tid];
      const int xmx = mn[2*S_ + tid], ymx = mn[3*S_ + tid];
      float4 v;
      v.x = (float)xmn; v.y = (float)ymn;
      v.z = (float)(xmx - xmn); v.w = (float)(ymx - ymn);
      ((float4*)(out + O_BBOX))[b * S_ + tid] = v;
    }
  } else if (bid < NBBOX + NTEX) {
    // ---------- texture hist plane (b, c*R+r): full image, final write ----------
    __builtin_amdgcn_s_setprio(1);
    const int plane = bid - NBBOX;          // b*24 + cr
    const int b = plane / (C_*R_);
    const int cr = plane - b * (C_*R_);
    int* h = (int*)smem;                    // S*TB = 10240 ints (40 KB)
    for (int i = tid; i < S_*TB_; i += 1024) h[i] = 0;
    __syncthreads();
    const int4* bp = (const int4*)(grads_bins + (size_t)plane * HW_);
    const int4* lp = (const int4*)(lab + (size_t)b * HW_);
    for (int t = tid; t < HW_/4; t += 1024) {
      const int4 bn = bp[t];
      const int4 lv = lp[t];
      atomicAdd(&h[lv.x*TB_ + bn.x], 1);
      atomicAdd(&h[lv.y*TB_ + bn.y], 1);
      atomicAdd(&h[lv.z*TB_ + bn.z], 1);
      atomicAdd(&h[lv.w*TB_ + bn.w], 1);
    }
    __syncthreads();
    __builtin_amdgcn_s_setprio(0);
    // thread l: area = sum of its 10 bins (full image) -> normalize + write
    {
      const int base = tid * TB_;
      int s = 0;
      #pragma unroll
      for (int t = 0; t < TB_; ++t) s += h[base + t];
      const float inv = 1.0f / ((float)s * 24.0f + 1e-12f);
      float* o = out + O_TEX + (size_t)b * (S_ * C_*R_*TB_) + tid * (C_*R_*TB_) + cr * TB_;
      #pragma unroll
      for (int t = 0; t < TB_; ++t) o[t] = (float)h[base + t] * inv;
      if (cr == 0) out[O_AREA + b * S_ + tid] = (float)s;
    }
  } else if (bid < NHIST) {
    // ---------- color hist plane (b,c): u16-packed LDS, final write ----------
    __builtin_amdgcn_s_setprio(1);
    const int plane = bid - NBBOX - NTEX;   // b*3 + c
    const int b = plane / C_;
    const int c = plane - b * C_;
    unsigned* h = smem;                     // S*CB/2 = 12800 words (51.2 KB)
    for (int i = tid; i < (S_*CB_)/2; i += 1024) h[i] = 0;
    __syncthreads();
    const int4* bp = (const int4*)(imgs_bins + (size_t)plane * HW_);
    const int4* lp = (const int4*)(lab + (size_t)b * HW_);
    for (int t = tid; t < HW_/4; t += 1024) {
      const int4 bn = bp[t];
      const int4 lv = lp[t];
      const int j0 = lv.x*CB_ + bn.x;
      const int j1 = lv.y*CB_ + bn.y;
      const int j2 = lv.z*CB_ + bn.z;
      const int j3 = lv.w*CB_ + bn.w;
      atomicAdd(&h[j0 >> 1], 1u << ((j0 & 1) << 4));
      atomicAdd(&h[j1 >> 1], 1u << ((j1 & 1) << 4));
      atomicAdd(&h[j2 >> 1], 1u << ((j2 & 1) << 4));
      atomicAdd(&h[j3 >> 1], 1u << ((j3 & 1) << 4));
    }
    __syncthreads();
    __builtin_amdgcn_s_setprio(0);
    // thread l: sum 25 bins -> normalize + write
    {
      int s = 0;
      #pragma unroll
      for (int ci = 0; ci < CB_; ++ci) {
        const int j = tid * CB_ + ci;
        s += (int)((h[j >> 1] >> ((j & 1) << 4)) & 0xFFFFu);
      }
      const float inv = 1.0f / ((float)s * 3.0f + 1e-12f);
      float* o = out + O_COLOR + (size_t)b * (S_ * C_*CB_) + tid * (C_*CB_) + c * CB_;
      #pragma unroll
      for (int ci = 0; ci < CB_; ++ci) {
        const int j = tid * CB_ + ci;
        o[ci] = (float)((h[j >> 1] >> ((j & 1) << 4)) & 0xFFFFu) * inv;
      }
    }
  } else {
    // ---------- Scharr gradients, grid-stride (bulk work, default prio) ----------
    const int cb = bid - NHIST;
    const int tot = B_*C_*HW_;
    for (int i = cb * 1024 + tid; i < tot; i += NCONV * 1024) {
      const int pix = i & (HW_ - 1);
      const int bc = i >> 18;
      const int x = pix & (W_ - 1);
      const int y = pix >> 9;
      const float* im = img + (size_t)bc * HW_;
      const bool xm = x > 0, xp = x < W_ - 1, ym = y > 0, yp = y < H_ - 1;
      const float i00 = (ym && xm) ? im[pix - W_ - 1] : 0.f;
      const float i01 = ym ? im[pix - W_] : 0.f;
      const float i02 = (ym && xp) ? im[pix - W_ + 1] : 0.f;
      const float i10 = xm ? im[pix - 1] : 0.f;
      const float i12 = xp ? im[pix + 1] : 0.f;
      const float i20 = (yp && xm) ? im[pix + W_ - 1] : 0.f;
      const float i21 = yp ? im[pix + W_] : 0.f;
      const float i22 = (yp && xp) ? im[pix + W_ + 1] : 0.f;
      const float gx = 3.f*(i02 - i00) + 10.f*(i12 - i10) + 3.f*(i22 - i20);
      const float gy = 3.f*(i20 - i00) + 10.f*(i21 - i01) + 3.f*(i22 - i02);
      out[O_GRADS + (size_t)(bc*2 + 0)*HW_ + pix] = gx;
      out[O_GRADS + (size_t)(bc*2 + 1)*HW_ + pix] = gy;
    }
  }
}

extern "C" void kernel_launch(void* const* d_in, const int* in_sizes, int n_in,
                              void* d_out, int out_size, void* d_ws, size_t ws_size,
                              hipStream_t stream) {
  const float* img = (const float*)d_in[0];
  const int* imgs_bins = (const int*)d_in[1];
  const int* grads_bins = (const int*)d_in[2];
  const int* reg_lab = (const int*)d_in[3];
  float* out = (float*)d_out;

  hipLaunchKernelGGL(k_fused, dim3(NGRID), dim3(1024), 0, stream,
                     img, imgs_bins, grads_bins, reg_lab, out);
}

// Round 11
// 76.921 us; speedup vs baseline: 1.1489x; 1.0301x over previous
//
#include <hip/hip_runtime.h>

#define B_ 8
#define C_ 3
#define R_ 8
#define H_ 512
#define W_ 512
#define HW_ (H_*W_)
#define S_ 1024
#define CB_ 25
#define TB_ 10

// output offsets (floats)
#define O_AREA 0
#define O_BBOX 8192
#define O_COLOR 40960
#define O_TEX 655360
#define O_GRADS 2621440
#define OUT_TOT 15204352

// block roles (R3 champion layout)
#define NBBOX 8
#define NTEX (B_*C_*R_)        // 192
#define NCOL (B_*C_)           // 24
#define NHIST (NBBOX + NTEX + NCOL)   // 224
#define NCONV 1024
#define NGRID (NHIST + NCONV)  // 1248

// packed-u16 label scratch: 2,097,152 u16 = 4 MB
#define PK_WORDS 1048576
#define NEED_WS ((size_t)PK_WORDS * 4)
#define SCR_OFF (OUT_TOT - PK_WORDS)   // overlays grads planes p>=44 (bc>=22)
#define CONV_SAFE (22 << 18)           // fused conv covers bc<22 in fallback
#define CONV_ALL  (24 << 18)

// ---------------- K0: pack labels int32 -> u16 (8 px / thread) ----------------
__global__ __launch_bounds__(1024) void k_pack(const int* __restrict__ lab,
                                               unsigned* __restrict__ plab) {
  const int i = blockIdx.x * 1024 + threadIdx.x;   // 262,144 threads
  const int4 a = ((const int4*)lab)[2 * i];
  const int4 b = ((const int4*)lab)[2 * i + 1];
  uint4 o;
  o.x = (unsigned)(a.x) | ((unsigned)a.y << 16);
  o.y = (unsigned)(a.z) | ((unsigned)a.w << 16);
  o.z = (unsigned)(b.x) | ((unsigned)b.y << 16);
  o.w = (unsigned)(b.z) | ((unsigned)b.w << 16);
  ((uint4*)plab)[i] = o;
}

// ---------------- K1: fused hist + bbox + conv (champion structure) ----------------
__global__ __launch_bounds__(1024) void k_fused(
    const float* __restrict__ img,
    const int* __restrict__ imgs_bins,
    const int* __restrict__ grads_bins,
    const unsigned* __restrict__ plab,   // packed u16 labels
    float* __restrict__ out,
    int convHi) {
  __shared__ unsigned smem[12800];   // 51.2 KB union
  const int bid = blockIdx.x;
  const int tid = threadIdx.x;

  if (bid < NBBOX) {
    // ---------- bbox for image b: LDS min/max, exclusive final write ----------
    const int b = bid;
    int* mn = (int*)smem;   // xmin[S], ymin[S], xmax[S], ymax[S]
    mn[tid] = W_; mn[S_ + tid] = H_; mn[2*S_ + tid] = 0; mn[3*S_ + tid] = 0;
    __syncthreads();
    const uint4* lp = (const uint4*)(plab + (size_t)b * (HW_/2));
    for (int t = tid; t < HW_/8; t += 1024) {
      const uint4 L = lp[t];
      const int p = t * 8;
      const int y = p >> 9;
      const int x = p & (W_ - 1);    // 8-aligned: x..x+7 same row
      #define BBX(l, xx) { const int ll = (int)(l); \
        atomicMin(&mn[ll], xx);        atomicMin(&mn[S_ + ll], y); \
        atomicMax(&mn[2*S_ + ll], xx); atomicMax(&mn[3*S_ + ll], y); }
      BBX(L.x & 0xFFFFu, x)     BBX(L.x >> 16, x + 1)
      BBX(L.y & 0xFFFFu, x + 2) BBX(L.y >> 16, x + 3)
      BBX(L.z & 0xFFFFu, x + 4) BBX(L.z >> 16, x + 5)
      BBX(L.w & 0xFFFFu, x + 6) BBX(L.w >> 16, x + 7)
      #undef BBX
    }
    __syncthreads();
    {
      const int xmn = mn[tid], ymn = mn[S_ + tid];
      const int xmx = mn[2*S_ + tid], ymx = mn[3*S_ + tid];
      float4 v;
      v.x = (float)xmn; v.y = (float)ymn;
      v.z = (float)(xmx - xmn); v.w = (float)(ymx - ymn);
      ((float4*)(out + O_BBOX))[b * S_ + tid] = v;
    }
  } else if (bid < NBBOX + NTEX) {
    // ---------- texture hist plane (b, cr): full image, final write ----------
    const int plane = bid - NBBOX;          // b*24 + cr
    const int b = plane / (C_*R_);
    const int cr = plane - b * (C_*R_);
    int* h = (int*)smem;                    // 10240 ints (40 KB)
    for (int i = tid; i < S_*TB_; i += 1024) h[i] = 0;
    __syncthreads();
    const int4* bp = (const int4*)(grads_bins + (size_t)plane * HW_);
    const uint4* lp = (const uint4*)(plab + (size_t)b * (HW_/2));
    for (int t = tid; t < HW_/8; t += 1024) {
      const uint4 L = lp[t];
      const int4 b0 = bp[2*t];
      const int4 b1 = bp[2*t + 1];
      atomicAdd(&h[(int)(L.x & 0xFFFFu)*TB_ + b0.x], 1);
      atomicAdd(&h[(int)(L.x >> 16)*TB_ + b0.y], 1);
      atomicAdd(&h[(int)(L.y & 0xFFFFu)*TB_ + b0.z], 1);
      atomicAdd(&h[(int)(L.y >> 16)*TB_ + b0.w], 1);
      atomicAdd(&h[(int)(L.z & 0xFFFFu)*TB_ + b1.x], 1);
      atomicAdd(&h[(int)(L.z >> 16)*TB_ + b1.y], 1);
      atomicAdd(&h[(int)(L.w & 0xFFFFu)*TB_ + b1.z], 1);
      atomicAdd(&h[(int)(L.w >> 16)*TB_ + b1.w], 1);
    }
    __syncthreads();
    {
      const int base = tid * TB_;
      int s = 0;
      #pragma unroll
      for (int t = 0; t < TB_; ++t) s += h[base + t];
      const float inv = 1.0f / ((float)s * 24.0f + 1e-12f);
      float* o = out + O_TEX + (size_t)b * (S_ * 240) + tid * 240 + cr * TB_;
      #pragma unroll
      for (int t = 0; t < TB_; ++t) o[t] = (float)h[base + t] * inv;
      if (cr == 0) out[O_AREA + b * S_ + tid] = (float)s;
    }
  } else if (bid < NHIST) {
    // ---------- color hist plane (b,c): u16-packed LDS, final write ----------
    const int plane = bid - NBBOX - NTEX;   // b*3 + c
    const int b = plane / C_;
    const int c = plane - b * C_;
    unsigned* h = smem;                     // 12800 words (51.2 KB)
    for (int i = tid; i < (S_*CB_)/2; i += 1024) h[i] = 0;
    __syncthreads();
    const int4* bp = (const int4*)(imgs_bins + (size_t)plane * HW_);
    const uint4* lp = (const uint4*)(plab + (size_t)b * (HW_/2));
    for (int t = tid; t < HW_/8; t += 1024) {
      const uint4 L = lp[t];
      const int4 b0 = bp[2*t];
      const int4 b1 = bp[2*t + 1];
      #define CADD(l, bin) { const int j = (int)(l)*CB_ + (bin); \
        atomicAdd(&h[j >> 1], 1u << ((j & 1) << 4)); }
      CADD(L.x & 0xFFFFu, b0.x) CADD(L.x >> 16, b0.y)
      CADD(L.y & 0xFFFFu, b0.z) CADD(L.y >> 16, b0.w)
      CADD(L.z & 0xFFFFu, b1.x) CADD(L.z >> 16, b1.y)
      CADD(L.w & 0xFFFFu, b1.z) CADD(L.w >> 16, b1.w)
      #undef CADD
    }
    __syncthreads();
    {
      int s = 0;
      #pragma unroll
      for (int ci = 0; ci < CB_; ++ci) {
        const int j = tid * CB_ + ci;
        s += (int)((h[j >> 1] >> ((j & 1) << 4)) & 0xFFFFu);
      }
      const float inv = 1.0f / ((float)s * 3.0f + 1e-12f);
      float* o = out + O_COLOR + (size_t)b * (S_ * 75) + tid * 75 + c * CB_;
      #pragma unroll
      for (int ci = 0; ci < CB_; ++ci) {
        const int j = tid * CB_ + ci;
        o[ci] = (float)((h[j >> 1] >> ((j & 1) << 4)) & 0xFFFFu) * inv;
      }
    }
  } else {
    // ---------- Scharr gradients, grid-stride ----------
    const int cb = bid - NHIST;
    for (int i = cb * 1024 + tid; i < convHi; i += NCONV * 1024) {
      const int pix = i & (HW_ - 1);
      const int bc = i >> 18;
      const int x = pix & (W_ - 1);
      const int y = pix >> 9;
      const float* im = img + (size_t)bc * HW_;
      const bool xm = x > 0, xp = x < W_ - 1, ym = y > 0, yp = y < H_ - 1;
      const float i00 = (ym && xm) ? im[pix - W_ - 1] : 0.f;
      const float i01 = ym ? im[pix - W_] : 0.f;
      const float i02 = (ym && xp) ? im[pix - W_ + 1] : 0.f;
      const float i10 = xm ? im[pix - 1] : 0.f;
      const float i12 = xp ? im[pix + 1] : 0.f;
      const float i20 = (yp && xm) ? im[pix + W_ - 1] : 0.f;
      const float i21 = yp ? im[pix + W_] : 0.f;
      const float i22 = (yp && xp) ? im[pix + W_ + 1] : 0.f;
      const float gx = 3.f*(i02 - i00) + 10.f*(i12 - i10) + 3.f*(i22 - i20);
      const float gy = 3.f*(i20 - i00) + 10.f*(i21 - i01) + 3.f*(i22 - i02);
      out[O_GRADS + (size_t)(bc*2 + 0)*HW_ + pix] = gx;
      out[O_GRADS + (size_t)(bc*2 + 1)*HW_ + pix] = gy;
    }
  }
}

// ---------------- K2 (fallback only): conv tail bc 22..23 ----------------
__global__ __launch_bounds__(1024) void k_conv_tail(const float* __restrict__ img,
                                                    float* __restrict__ out) {
  const int i = CONV_SAFE + blockIdx.x * 1024 + threadIdx.x;
  const int pix = i & (HW_ - 1);
  const int bc = i >> 18;
  const int x = pix & (W_ - 1);
  const int y = pix >> 9;
  const float* im = img + (size_t)bc * HW_;
  const bool xm = x > 0, xp = x < W_ - 1, ym = y > 0, yp = y < H_ - 1;
  const float i00 = (ym && xm) ? im[pix - W_ - 1] : 0.f;
  const float i01 = ym ? im[pix - W_] : 0.f;
  const float i02 = (ym && xp) ? im[pix - W_ + 1] : 0.f;
  const float i10 = xm ? im[pix - 1] : 0.f;
  const float i12 = xp ? im[pix + 1] : 0.f;
  const float i20 = (yp && xm) ? im[pix + W_ - 1] : 0.f;
  const float i21 = yp ? im[pix + W_] : 0.f;
  const float i22 = (yp && xp) ? im[pix + W_ + 1] : 0.f;
  const float gx = 3.f*(i02 - i00) + 10.f*(i12 - i10) + 3.f*(i22 - i20);
  const float gy = 3.f*(i20 - i00) + 10.f*(i21 - i01) + 3.f*(i22 - i02);
  out[O_GRADS + (size_t)(bc*2 + 0)*HW_ + pix] = gx;
  out[O_GRADS + (size_t)(bc*2 + 1)*HW_ + pix] = gy;
}

extern "C" void kernel_launch(void* const* d_in, const int* in_sizes, int n_in,
                              void* d_out, int out_size, void* d_ws, size_t ws_size,
                              hipStream_t stream) {
  const float* img = (const float*)d_in[0];
  const int* imgs_bins = (const int*)d_in[1];
  const int* grads_bins = (const int*)d_in[2];
  const int* reg_lab = (const int*)d_in[3];
  float* out = (float*)d_out;

  const bool ws_ok = ws_size >= NEED_WS;
  unsigned* plab = ws_ok ? (unsigned*)d_ws : (unsigned*)(out + SCR_OFF);
  const int convHi = ws_ok ? CONV_ALL : CONV_SAFE;

  hipLaunchKernelGGL(k_pack, dim3(256), dim3(1024), 0, stream, reg_lab, plab);
  hipLaunchKernelGGL(k_fused, dim3(NGRID), dim3(1024), 0, stream,
                     img, imgs_bins, grads_bins, plab, out, convHi);
  if (!ws_ok) {
    hipLaunchKernelGGL(k_conv_tail, dim3(512), dim3(1024), 0, stream, img, out);
  }
}